// Round 3
// baseline (384.910 us; speedup 1.0000x reference)
//
#include <hip/hip_runtime.h>
#include <hip/hip_bf16.h>

#define T_SEQ 4096
#define NB 4
#define CEMB 2048
#define HS 128

typedef __attribute__((ext_vector_type(8))) short bf16x8;
typedef __attribute__((ext_vector_type(4))) float f32x4;

__device__ inline short f2bf(float f) {
    union { float f; unsigned u; } v; v.f = f;
    unsigned r = v.u + 0x7FFFu + ((v.u >> 16) & 1u);   // RNE
    return (short)(r >> 16);
}

// ---------------- kernel 1: W -> Wt[mat][n][k] bf16 (mat: 0=q,1=k,2=v) -------
__global__ __launch_bounds__(256) void wt_kernel(
    const float* __restrict__ Wq, const float* __restrict__ Wk,
    const float* __restrict__ Wv, short* __restrict__ Wt) {
    int idx = blockIdx.x * 256 + threadIdx.x;   // 3*128*2048 = 786432
    int mat = idx >> 18;                        // 262144 per matrix
    int rem = idx & 262143;
    int n = rem >> 11;                          // 0..127
    int k = rem & 2047;                         // 0..2047
    const float* W = (mat == 0) ? Wq : (mat == 1) ? Wk : Wv;
    Wt[idx] = f2bf(W[k * HS + n]);
}

// ---------------- kernel 2: q/k/v projection, one matrix per block -----------
// grid 768: bid%3 = matrix (0=q,1=k,2=v), bid/3 = 64-row m-tile.
// q,k: bf16 [B*T][128] ; v stored transposed: bf16 [B][128][T]
__global__ __launch_bounds__(256, 3) void proj_kernel(
    const float* __restrict__ x, const short* __restrict__ Wt,
    short* __restrict__ qg, short* __restrict__ kg, short* __restrict__ vtg) {
    const int tid = threadIdx.x;
    const int bid = blockIdx.x;
    const int mat = bid % 3;
    const int m0  = (bid / 3) * 64;
    const int w   = tid >> 6;
    const int l   = tid & 63;
    const int lg  = l >> 4;     // 0..3  (selects k-subrange of the fragment)
    const int lr  = l & 15;     // 0..15 (selects row/col of the fragment)

    f32x4 acc[8];
    #pragma unroll
    for (int b = 0; b < 8; b++) acc[b] = (f32x4){0.f, 0.f, 0.f, 0.f};

    const short* Wm = Wt + (long)mat * 262144;

    // A-fragment source: row m0 + w*16 + lr, cols k0 + lg*8 .. +7
    // Lanes {lr, lr+16, lr+32, lr+48} cover 32 consecutive k of one row
    // = 128 contiguous bytes -> fully coalesced without LDS.
    const float* xrow = x + (long)(m0 + w * 16 + lr) * CEMB + lg * 8;

    float4 c0 = *reinterpret_cast<const float4*>(xrow);
    float4 c1 = *reinterpret_cast<const float4*>(xrow + 4);

    #pragma unroll 2
    for (int k0 = 0; k0 < CEMB; k0 += 32) {
        // ---- prefetch next K-step's x ----
        float4 n0 = c0, n1 = c1;
        if (k0 + 32 < CEMB) {
            n0 = *reinterpret_cast<const float4*>(xrow + k0 + 32);
            n1 = *reinterpret_cast<const float4*>(xrow + k0 + 36);
        }

        // ---- current A fragment ----
        bf16x8 afr;
        afr[0] = f2bf(c0.x); afr[1] = f2bf(c0.y); afr[2] = f2bf(c0.z); afr[3] = f2bf(c0.w);
        afr[4] = f2bf(c1.x); afr[5] = f2bf(c1.y); afr[6] = f2bf(c1.z); afr[7] = f2bf(c1.w);

        const long kbase = (long)k0 + lg * 8;
        #pragma unroll
        for (int nt = 0; nt < 8; nt++) {
            bf16x8 bfr = *reinterpret_cast<const bf16x8*>(
                &Wm[(long)(nt * 16 + lr) * CEMB + kbase]);
            acc[nt] = __builtin_amdgcn_mfma_f32_16x16x32_bf16(
                afr, bfr, acc[nt], 0, 0, 0);
        }
        c0 = n0; c1 = n1;
    }

    // ---- store (D layout: col=l&15, row=(l>>4)*4+reg) ----
    if (mat == 0) {
        #pragma unroll
        for (int nt = 0; nt < 8; nt++)
            #pragma unroll
            for (int r = 0; r < 4; r++) {
                int row = m0 + w * 16 + lg * 4 + r;
                qg[(long)row * HS + nt * 16 + lr] = f2bf(acc[nt][r]);
            }
    } else if (mat == 1) {
        #pragma unroll
        for (int nt = 0; nt < 8; nt++)
            #pragma unroll
            for (int r = 0; r < 4; r++) {
                int row = m0 + w * 16 + lg * 4 + r;
                kg[(long)row * HS + nt * 16 + lr] = f2bf(acc[nt][r]);
            }
    } else {
        #pragma unroll
        for (int nt = 0; nt < 8; nt++)
            #pragma unroll
            for (int r = 0; r < 4; r++) {
                int row = m0 + w * 16 + lg * 4 + r;
                int b   = row >> 12;
                int tl  = row & 4095;
                vtg[(long)b * (HS * T_SEQ) + (long)(nt * 16 + lr) * T_SEQ + tl]
                    = f2bf(acc[nt][r]);
            }
    }
}

// ---------------- kernel 3: causal flash attention ---------------------------
__global__ __launch_bounds__(128) void attn_kernel(
    const short* __restrict__ qg, const short* __restrict__ kg,
    const short* __restrict__ vtg, float* __restrict__ out) {
    __shared__ short K_lds[64][136];   // [kv][d]  pad: 2-way alias only
    __shared__ short V_lds[128][72];   // [d][kv]
    __shared__ short P_lds[2][16][72]; // per wave [qrow][kv]

    const int tid = threadIdx.x;
    const int w   = tid >> 6;
    const int l   = tid & 63;
    const int lg  = l >> 4;
    const int lr  = l & 15;

    const int bid = blockIdx.x;
    const int b   = bid & 3;
    const int qt  = 127 - (bid >> 2);   // longest tiles scheduled first
    const int q0  = qt * 32;

    // Q fragments in registers (rows w*16+lr, all 128 d)
    bf16x8 qf[4];
    #pragma unroll
    for (int ks = 0; ks < 4; ks++)
        qf[ks] = *reinterpret_cast<const bf16x8*>(
            &qg[((long)(b * T_SEQ + q0 + w * 16 + lr)) * HS + ks * 32 + lg * 8]);

    f32x4 acc[8];
    #pragma unroll
    for (int nt = 0; nt < 8; nt++) acc[nt] = (f32x4){0.f, 0.f, 0.f, 0.f};
    float mrow[4] = {-__builtin_inff(), -__builtin_inff(), -__builtin_inff(), -__builtin_inff()};
    float lsum[4] = {0.f, 0.f, 0.f, 0.f};

    const float scale = 0.022097086912079612f;  // 2048^-0.5
    const int ntk = ((q0 + 31) >> 6) + 1;

    for (int it = 0; it < ntk; ++it) {
        const int kv0 = it * 64;
        // ---- stage K (64x128) and Vt (128x64) ----
        {
            int r  = tid >> 1;
            int c0 = (tid & 1) * 64;
            const bf16x8* srcK = reinterpret_cast<const bf16x8*>(
                &kg[((long)(b * T_SEQ + kv0 + r)) * HS + c0]);
            const bf16x8* srcV = reinterpret_cast<const bf16x8*>(
                &vtg[(long)b * (HS * T_SEQ) + (long)tid * T_SEQ + kv0]);
            bf16x8 kv[8], vv[8];
            #pragma unroll
            for (int j = 0; j < 8; j++) kv[j] = srcK[j];
            #pragma unroll
            for (int j = 0; j < 8; j++) vv[j] = srcV[j];
            __syncthreads();   // previous iteration's LDS reads complete
            #pragma unroll
            for (int j = 0; j < 8; j++)
                *reinterpret_cast<bf16x8*>(&K_lds[r][c0 + j * 8]) = kv[j];
            #pragma unroll
            for (int j = 0; j < 8; j++)
                *reinterpret_cast<bf16x8*>(&V_lds[tid][j * 8]) = vv[j];
            __syncthreads();
        }

        // ---- S = Q @ K^T (16 x 64 per wave) ----
        f32x4 s[4];
        #pragma unroll
        for (int nt = 0; nt < 4; nt++) {
            s[nt] = (f32x4){0.f, 0.f, 0.f, 0.f};
            #pragma unroll
            for (int ks = 0; ks < 4; ks++) {
                bf16x8 kf = *reinterpret_cast<const bf16x8*>(
                    &K_lds[nt * 16 + lr][ks * 32 + lg * 8]);
                s[nt] = __builtin_amdgcn_mfma_f32_16x16x32_bf16(qf[ks], kf, s[nt], 0, 0, 0);
            }
        }

        // ---- online softmax (rows (l>>4)*4+r, cols l&15 + 16nt) ----
        float pv[4][4];
        #pragma unroll
        for (int nt = 0; nt < 4; nt++)
            #pragma unroll
            for (int r = 0; r < 4; r++) {
                float vq = s[nt][r] * scale;
                int qi = q0 + w * 16 + lg * 4 + r;
                int kj = kv0 + nt * 16 + lr;
                if (kj > qi) vq = -__builtin_inff();
                pv[nt][r] = vq;
            }
        float mnew[4], fac[4];
        #pragma unroll
        for (int r = 0; r < 4; r++) {
            float t = fmaxf(fmaxf(pv[0][r], pv[1][r]), fmaxf(pv[2][r], pv[3][r]));
            t = fmaxf(t, __shfl_xor(t, 1));
            t = fmaxf(t, __shfl_xor(t, 2));
            t = fmaxf(t, __shfl_xor(t, 4));
            t = fmaxf(t, __shfl_xor(t, 8));
            mnew[r] = fmaxf(mrow[r], t);
            fac[r]  = __expf(mrow[r] - mnew[r]);   // first tile: exp(-inf)=0
        }
        #pragma unroll
        for (int nt = 0; nt < 4; nt++)
            #pragma unroll
            for (int r = 0; r < 4; r++)
                pv[nt][r] = __expf(pv[nt][r] - mnew[r]);   // masked -> 0
        #pragma unroll
        for (int r = 0; r < 4; r++) {
            float t = pv[0][r] + pv[1][r] + pv[2][r] + pv[3][r];
            t += __shfl_xor(t, 1);
            t += __shfl_xor(t, 2);
            t += __shfl_xor(t, 4);
            t += __shfl_xor(t, 8);
            lsum[r] = lsum[r] * fac[r] + t;
            mrow[r] = mnew[r];
        }
        #pragma unroll
        for (int nt = 0; nt < 8; nt++)
            #pragma unroll
            for (int r = 0; r < 4; r++) acc[nt][r] *= fac[r];

        // ---- P -> LDS (transpose to A-fragment layout) ----
        #pragma unroll
        for (int nt = 0; nt < 4; nt++)
            #pragma unroll
            for (int r = 0; r < 4; r++)
                P_lds[w][lg * 4 + r][nt * 16 + lr] = f2bf(pv[nt][r]);
        __syncthreads();

        // ---- O += P @ V ----
        #pragma unroll
        for (int ks = 0; ks < 2; ks++) {
            bf16x8 pa = *reinterpret_cast<const bf16x8*>(&P_lds[w][lr][ks * 32 + lg * 8]);
            #pragma unroll
            for (int nt = 0; nt < 8; nt++) {
                bf16x8 vb = *reinterpret_cast<const bf16x8*>(
                    &V_lds[nt * 16 + lr][ks * 32 + lg * 8]);
                acc[nt] = __builtin_amdgcn_mfma_f32_16x16x32_bf16(pa, vb, acc[nt], 0, 0, 0);
            }
        }
    }

    // ---- epilogue: O / l ----
    #pragma unroll
    for (int nt = 0; nt < 8; nt++)
        #pragma unroll
        for (int r = 0; r < 4; r++) {
            int row = q0 + w * 16 + lg * 4 + r;
            out[((long)b * T_SEQ + row) * HS + nt * 16 + lr] = acc[nt][r] / lsum[r];
        }
}

// ---------------- launch ------------------------------------------------------
extern "C" void kernel_launch(void* const* d_in, const int* in_sizes, int n_in,
                              void* d_out, int out_size, void* d_ws, size_t ws_size,
                              hipStream_t stream) {
    const float* x  = (const float*)d_in[0];
    const float* Wk = (const float*)d_in[1];
    const float* Wq = (const float*)d_in[2];
    const float* Wv = (const float*)d_in[3];
    float* out = (float*)d_out;

    char* ws = (char*)d_ws;
    short* Wt  = (short*)ws;                                  // 1.5 MB
    short* qg  = (short*)(ws + 1572864);                      // 4 MB
    short* kg  = (short*)(ws + 1572864 + 4194304);            // 4 MB
    short* vtg = (short*)(ws + 1572864 + 8388608);            // 4 MB

    wt_kernel  <<<3072, 256, 0, stream>>>(Wq, Wk, Wv, Wt);
    proj_kernel<<<768,  256, 0, stream>>>(x, Wt, qg, kg, vtg);
    attn_kernel<<<512,  128, 0, stream>>>(qg, kg, vtg, out);
}

// Round 4
// 236.746 us; speedup vs baseline: 1.6258x; 1.6258x over previous
//
#include <hip/hip_runtime.h>
#include <hip/hip_bf16.h>

#define T_SEQ 4096
#define NB 4
#define CEMB 2048
#define HS 128

typedef __attribute__((ext_vector_type(8))) short bf16x8;
typedef __attribute__((ext_vector_type(4))) float f32x4;

__device__ inline short f2bf(float f) {
    union { float f; unsigned u; } v; v.f = f;
    unsigned r = v.u + 0x7FFFu + ((v.u >> 16) & 1u);   // RNE
    return (short)(r >> 16);
}

__device__ inline void gld16(const void* gsrc, void* lds) {
    __builtin_amdgcn_global_load_lds(
        (const __attribute__((address_space(1))) unsigned*)gsrc,
        (__attribute__((address_space(3))) unsigned*)lds, 16, 0, 0);
}

// ---------------- kernel 1: W -> pre-swizzled bf16 LDS-image panels ----------
// Wt[mat][panel s][16KB panel], panel layout: byte = (n*128 + kk*2) ^ ((n&7)<<4)
// with n = output col (0..127), kk = k - s*64 (0..63). mat: 0=q,1=k,2=v.
__global__ __launch_bounds__(256) void wt_kernel(
    const float* __restrict__ Wq, const float* __restrict__ Wk,
    const float* __restrict__ Wv, short* __restrict__ Wt) {
    int d = blockIdx.x * 256 + threadIdx.x;     // 3*32*8192 = 786432
    int mat = d >> 18;                          // 262144 per matrix
    int rm  = d & 262143;
    int s   = rm >> 13;                         // panel 0..31
    int e   = rm & 8191;                        // element within panel
    int p   = e * 2;                            // stored byte offset
    int n   = p >> 7;                           // row preserved by swizzle
    int lin = p ^ ((n & 7) << 4);               // linear byte within panel
    int kk  = (lin & 127) >> 1;
    int k   = s * 64 + kk;
    const float* W = (mat == 0) ? Wq : (mat == 1) ? Wk : Wv;
    Wt[d] = f2bf(W[k * HS + n]);
}

// ---------------- kernel 2: q/k/v projection, 2-phase LDS pipeline -----------
// grid 768, XCD-chunked: wk = (bid&7)*96 + (bid>>3); mat = wk%3; mtile = wk/3.
// q,k: bf16 [B*T][128] ; v stored transposed: bf16 [B][128][T]
__global__ __launch_bounds__(256, 3) void proj_kernel(
    const float* __restrict__ x, const short* __restrict__ Wt,
    short* __restrict__ qg, short* __restrict__ kg, short* __restrict__ vtg) {
    __shared__ short Wlds[2][8192];   // 2 x 16KB panels

    const int tid = threadIdx.x;
    const int w   = tid >> 6;
    const int l   = tid & 63;
    const int lg  = l >> 4;     // 0..3
    const int lr  = l & 15;     // 0..15

    const int bid = blockIdx.x;
    const int wk  = (bid & 7) * 96 + (bid >> 3);   // same-XCD chunking
    const int mat = wk % 3;
    const int m0  = (wk / 3) * 64;

    const short* Wp = Wt + (long)mat * 262144;     // 32 panels of 8192 shorts

    f32x4 acc[8];
    #pragma unroll
    for (int b = 0; b < 8; b++) acc[b] = (f32x4){0.f, 0.f, 0.f, 0.f};

    // x source: row m0 + w*16 + lr
    const float* xrow = x + (long)(m0 + w * 16 + lr) * CEMB;

    // per-lane swizzled LDS byte offsets for the 16 B-fragments
    const int sw = (lr & 7) << 4;

    // ---- prologue: stage panel 0, preload x k-step 0 ----
    {
        const short* gp = Wp + (long)(w * 4) * 512 + l * 8;
        #pragma unroll
        for (int j = 0; j < 4; j++)
            gld16(gp + j * 512, &Wlds[0][(w * 4 + j) * 512]);
    }
    float4 c0 = *reinterpret_cast<const float4*>(xrow + lg * 8);
    float4 c1 = *reinterpret_cast<const float4*>(xrow + lg * 8 + 4);
    float4 c2 = *reinterpret_cast<const float4*>(xrow + 32 + lg * 8);
    float4 c3 = *reinterpret_cast<const float4*>(xrow + 32 + lg * 8 + 4);
    __syncthreads();

    #pragma unroll 2
    for (int s = 0; s < 32; ++s) {
        const int cur = s & 1;

        // ---- stage next panel + prefetch next x ----
        float4 n0 = c0, n1 = c1, n2 = c2, n3 = c3;
        if (s < 31) {
            const short* gp = Wp + (long)(s + 1) * 8192 + (long)(w * 4) * 512 + l * 8;
            #pragma unroll
            for (int j = 0; j < 4; j++)
                gld16(gp + j * 512, &Wlds[cur ^ 1][(w * 4 + j) * 512]);
            const float* xn = xrow + (s + 1) * 64 + lg * 8;
            n0 = *reinterpret_cast<const float4*>(xn);
            n1 = *reinterpret_cast<const float4*>(xn + 4);
            n2 = *reinterpret_cast<const float4*>(xn + 32);
            n3 = *reinterpret_cast<const float4*>(xn + 36);
        }

        // ---- A fragments (ks = 0,1) ----
        bf16x8 a0, a1;
        a0[0] = f2bf(c0.x); a0[1] = f2bf(c0.y); a0[2] = f2bf(c0.z); a0[3] = f2bf(c0.w);
        a0[4] = f2bf(c1.x); a0[5] = f2bf(c1.y); a0[6] = f2bf(c1.z); a0[7] = f2bf(c1.w);
        a1[0] = f2bf(c2.x); a1[1] = f2bf(c2.y); a1[2] = f2bf(c2.z); a1[3] = f2bf(c2.w);
        a1[4] = f2bf(c3.x); a1[5] = f2bf(c3.y); a1[6] = f2bf(c3.z); a1[7] = f2bf(c3.w);

        // ---- B fragments from LDS (swizzled) + MFMA ----
        const char* lbase = (const char*)&Wlds[cur][0];
        #pragma unroll
        for (int ks = 0; ks < 2; ks++) {
            const bf16x8 afr = ks ? a1 : a0;
            #pragma unroll
            for (int nt = 0; nt < 8; nt++) {
                int off = (((nt * 16 + lr) * 128 + lg * 16 + ks * 64)) ^ sw;
                bf16x8 bfr = *reinterpret_cast<const bf16x8*>(lbase + off);
                acc[nt] = __builtin_amdgcn_mfma_f32_16x16x32_bf16(
                    afr, bfr, acc[nt], 0, 0, 0);
            }
        }

        __syncthreads();   // vmcnt(0)+lgkmcnt(0)+barrier: next panel ready
        c0 = n0; c1 = n1; c2 = n2; c3 = n3;
    }

    // ---- store (D layout: col=l&15, row=(l>>4)*4+reg) ----
    if (mat == 0) {
        #pragma unroll
        for (int nt = 0; nt < 8; nt++)
            #pragma unroll
            for (int r = 0; r < 4; r++) {
                int row = m0 + w * 16 + lg * 4 + r;
                qg[(long)row * HS + nt * 16 + lr] = f2bf(acc[nt][r]);
            }
    } else if (mat == 1) {
        #pragma unroll
        for (int nt = 0; nt < 8; nt++)
            #pragma unroll
            for (int r = 0; r < 4; r++) {
                int row = m0 + w * 16 + lg * 4 + r;
                kg[(long)row * HS + nt * 16 + lr] = f2bf(acc[nt][r]);
            }
    } else {
        #pragma unroll
        for (int nt = 0; nt < 8; nt++)
            #pragma unroll
            for (int r = 0; r < 4; r++) {
                int row = m0 + w * 16 + lg * 4 + r;
                int b   = row >> 12;
                int tl  = row & 4095;
                vtg[(long)b * (HS * T_SEQ) + (long)(nt * 16 + lr) * T_SEQ + tl]
                    = f2bf(acc[nt][r]);
            }
    }
}

// ---------------- kernel 3: causal flash attention ---------------------------
__global__ __launch_bounds__(128) void attn_kernel(
    const short* __restrict__ qg, const short* __restrict__ kg,
    const short* __restrict__ vtg, float* __restrict__ out) {
    __shared__ short K_lds[64][136];   // [kv][d]  pad: 2-way alias only
    __shared__ short V_lds[128][72];   // [d][kv]
    __shared__ short P_lds[2][16][72]; // per wave [qrow][kv]

    const int tid = threadIdx.x;
    const int w   = tid >> 6;
    const int l   = tid & 63;
    const int lg  = l >> 4;
    const int lr  = l & 15;

    const int bid = blockIdx.x;
    const int b   = bid & 3;
    const int qt  = 127 - (bid >> 2);   // longest tiles scheduled first
    const int q0  = qt * 32;

    // Q fragments in registers (rows w*16+lr, all 128 d)
    bf16x8 qf[4];
    #pragma unroll
    for (int ks = 0; ks < 4; ks++)
        qf[ks] = *reinterpret_cast<const bf16x8*>(
            &qg[((long)(b * T_SEQ + q0 + w * 16 + lr)) * HS + ks * 32 + lg * 8]);

    f32x4 acc[8];
    #pragma unroll
    for (int nt = 0; nt < 8; nt++) acc[nt] = (f32x4){0.f, 0.f, 0.f, 0.f};
    float mrow[4] = {-__builtin_inff(), -__builtin_inff(), -__builtin_inff(), -__builtin_inff()};
    float lsum[4] = {0.f, 0.f, 0.f, 0.f};

    const float scale = 0.022097086912079612f;  // 2048^-0.5
    const int ntk = ((q0 + 31) >> 6) + 1;

    for (int it = 0; it < ntk; ++it) {
        const int kv0 = it * 64;
        // ---- stage K (64x128) and Vt (128x64) ----
        {
            int r  = tid >> 1;
            int c0 = (tid & 1) * 64;
            const bf16x8* srcK = reinterpret_cast<const bf16x8*>(
                &kg[((long)(b * T_SEQ + kv0 + r)) * HS + c0]);
            const bf16x8* srcV = reinterpret_cast<const bf16x8*>(
                &vtg[(long)b * (HS * T_SEQ) + (long)tid * T_SEQ + kv0]);
            bf16x8 kv[8], vv[8];
            #pragma unroll
            for (int j = 0; j < 8; j++) kv[j] = srcK[j];
            #pragma unroll
            for (int j = 0; j < 8; j++) vv[j] = srcV[j];
            __syncthreads();   // previous iteration's LDS reads complete
            #pragma unroll
            for (int j = 0; j < 8; j++)
                *reinterpret_cast<bf16x8*>(&K_lds[r][c0 + j * 8]) = kv[j];
            #pragma unroll
            for (int j = 0; j < 8; j++)
                *reinterpret_cast<bf16x8*>(&V_lds[tid][j * 8]) = vv[j];
            __syncthreads();
        }

        // ---- S = Q @ K^T (16 x 64 per wave) ----
        f32x4 s[4];
        #pragma unroll
        for (int nt = 0; nt < 4; nt++) {
            s[nt] = (f32x4){0.f, 0.f, 0.f, 0.f};
            #pragma unroll
            for (int ks = 0; ks < 4; ks++) {
                bf16x8 kf = *reinterpret_cast<const bf16x8*>(
                    &K_lds[nt * 16 + lr][ks * 32 + lg * 8]);
                s[nt] = __builtin_amdgcn_mfma_f32_16x16x32_bf16(qf[ks], kf, s[nt], 0, 0, 0);
            }
        }

        // ---- online softmax (rows (l>>4)*4+r, cols l&15 + 16nt) ----
        float pv[4][4];
        #pragma unroll
        for (int nt = 0; nt < 4; nt++)
            #pragma unroll
            for (int r = 0; r < 4; r++) {
                float vq = s[nt][r] * scale;
                int qi = q0 + w * 16 + lg * 4 + r;
                int kj = kv0 + nt * 16 + lr;
                if (kj > qi) vq = -__builtin_inff();
                pv[nt][r] = vq;
            }
        float mnew[4], fac[4];
        #pragma unroll
        for (int r = 0; r < 4; r++) {
            float t = fmaxf(fmaxf(pv[0][r], pv[1][r]), fmaxf(pv[2][r], pv[3][r]));
            t = fmaxf(t, __shfl_xor(t, 1));
            t = fmaxf(t, __shfl_xor(t, 2));
            t = fmaxf(t, __shfl_xor(t, 4));
            t = fmaxf(t, __shfl_xor(t, 8));
            mnew[r] = fmaxf(mrow[r], t);
            fac[r]  = __expf(mrow[r] - mnew[r]);   // first tile: exp(-inf)=0
        }
        #pragma unroll
        for (int nt = 0; nt < 4; nt++)
            #pragma unroll
            for (int r = 0; r < 4; r++)
                pv[nt][r] = __expf(pv[nt][r] - mnew[r]);   // masked -> 0
        #pragma unroll
        for (int r = 0; r < 4; r++) {
            float t = pv[0][r] + pv[1][r] + pv[2][r] + pv[3][r];
            t += __shfl_xor(t, 1);
            t += __shfl_xor(t, 2);
            t += __shfl_xor(t, 4);
            t += __shfl_xor(t, 8);
            lsum[r] = lsum[r] * fac[r] + t;
            mrow[r] = mnew[r];
        }
        #pragma unroll
        for (int nt = 0; nt < 8; nt++)
            #pragma unroll
            for (int r = 0; r < 4; r++) acc[nt][r] *= fac[r];

        // ---- P -> LDS (transpose to A-fragment layout) ----
        #pragma unroll
        for (int nt = 0; nt < 4; nt++)
            #pragma unroll
            for (int r = 0; r < 4; r++)
                P_lds[w][lg * 4 + r][nt * 16 + lr] = f2bf(pv[nt][r]);
        __syncthreads();

        // ---- O += P @ V ----
        #pragma unroll
        for (int ks = 0; ks < 2; ks++) {
            bf16x8 pa = *reinterpret_cast<const bf16x8*>(&P_lds[w][lr][ks * 32 + lg * 8]);
            #pragma unroll
            for (int nt = 0; nt < 8; nt++) {
                bf16x8 vb = *reinterpret_cast<const bf16x8*>(
                    &V_lds[nt * 16 + lr][ks * 32 + lg * 8]);
                acc[nt] = __builtin_amdgcn_mfma_f32_16x16x32_bf16(pa, vb, acc[nt], 0, 0, 0);
            }
        }
    }

    // ---- epilogue: O / l ----
    #pragma unroll
    for (int nt = 0; nt < 8; nt++)
        #pragma unroll
        for (int r = 0; r < 4; r++) {
            int row = q0 + w * 16 + lg * 4 + r;
            out[((long)b * T_SEQ + row) * HS + nt * 16 + lr] = acc[nt][r] / lsum[r];
        }
}

// ---------------- launch ------------------------------------------------------
extern "C" void kernel_launch(void* const* d_in, const int* in_sizes, int n_in,
                              void* d_out, int out_size, void* d_ws, size_t ws_size,
                              hipStream_t stream) {
    const float* x  = (const float*)d_in[0];
    const float* Wk = (const float*)d_in[1];
    const float* Wq = (const float*)d_in[2];
    const float* Wv = (const float*)d_in[3];
    float* out = (float*)d_out;

    char* ws = (char*)d_ws;
    short* Wt  = (short*)ws;                                  // 1.5 MB (swizzled panels)
    short* qg  = (short*)(ws + 1572864);                      // 4 MB
    short* kg  = (short*)(ws + 1572864 + 4194304);            // 4 MB
    short* vtg = (short*)(ws + 1572864 + 8388608);            // 4 MB

    wt_kernel  <<<3072, 256, 0, stream>>>(Wq, Wk, Wv, Wt);
    proj_kernel<<<768,  256, 0, stream>>>(x, Wt, qg, kg, vtg);
    attn_kernel<<<512,  128, 0, stream>>>(qg, kg, vtg, out);
}